// Round 3
// baseline (182.855 us; speedup 1.0000x reference)
//
#include <hip/hip_runtime.h>
#include <hip/hip_bf16.h>

#define BB 2
#define SS 2048
#define DD 1024
#define HH 16
#define DKK 64
#define MM (BB * SS)                 // 4096
#define PER ((size_t)MM * DD)        // 4194304 elements per activation buffer

typedef __bf16 v8bf __attribute__((ext_vector_type(8)));
typedef float  v4f  __attribute__((ext_vector_type(4)));

// ---------- helpers ----------
__device__ __forceinline__ float bf2f(unsigned int u16) {
    union { unsigned int i; float f; } x;
    x.i = u16 << 16;
    return x.f;
}
__device__ __forceinline__ unsigned int pack2(float a, float b) {
    union { __hip_bfloat16 h; unsigned short u; } x, y;
    x.h = __float2bfloat16(a); y.h = __float2bfloat16(b);
    return (unsigned int)x.u | ((unsigned int)y.u << 16);
}
__device__ __forceinline__ unsigned short f2bfu(float v) {
    union { __hip_bfloat16 h; unsigned short u; } x;
    x.h = __float2bfloat16(v);
    return x.u;
}
template<bool BF>
__device__ __forceinline__ void ld4(const void* p, size_t i, float* f) {
    if (BF) {
        const uint2 u = *(const uint2*)((const unsigned short*)p + i);
        f[0] = bf2f(u.x & 0xffffu); f[1] = bf2f(u.x >> 16);
        f[2] = bf2f(u.y & 0xffffu); f[3] = bf2f(u.y >> 16);
    } else {
        const float4 v = *(const float4*)((const float*)p + i);
        f[0] = v.x; f[1] = v.y; f[2] = v.z; f[3] = v.w;
    }
}
template<bool BF>
__device__ __forceinline__ void st1(void* p, size_t i, float v) {
    if (BF) ((__hip_bfloat16*)p)[i] = __float2bfloat16(v);
    else    ((float*)p)[i] = v;
}
template<bool BF>
__device__ __forceinline__ uint4 ld8bf(const void* p, size_t i) {
    if (BF) return *(const uint4*)((const unsigned short*)p + i);
    float f[8];
    ld4<false>(p, i, f);
    ld4<false>(p, i + 4, f + 4);
    uint4 u;
    u.x = pack2(f[0], f[1]); u.y = pack2(f[2], f[3]);
    u.z = pack2(f[4], f[5]); u.w = pack2(f[6], f[7]);
    return u;
}

// 16B async global->LDS DMA. LDS dest = wave-uniform base + lane*16.
typedef const __attribute__((address_space(1))) void* gas_p;
typedef __attribute__((address_space(3))) void* las_p;
__device__ __forceinline__ void gld16(const void* g, void* l) {
    __builtin_amdgcn_global_load_lds(
        (gas_p)(unsigned long long)g,
        (las_p)(unsigned int)(unsigned long long)l,
        16, 0, 0);
}

// Inline dtype sniff (ballot over identical 64 words -> uniform decision).
__device__ __forceinline__ bool sniff_bf(const void* x) {
    const unsigned int w = ((const unsigned int*)x)[threadIdx.x & 63];
    const int e = (w >> 7) & 0xFF;
    return __popcll(__ballot(e >= 100 && e <= 140)) >= 32;
}

// ---------------------------------------------------------------------------
// Kernel 0: one-time bf16 precast of X and the four weight matrices, PLUS the
// RoPE cos/sin table (2048 positions x 32 freqs, float2). Table is computed
// with the exact same __expf/__sincosf sequence the old epilogue used, so
// numerics are bit-identical.
// ---------------------------------------------------------------------------
__global__ __launch_bounds__(256) void precast(
    const void* __restrict__ X,  const void* __restrict__ Wq,
    const void* __restrict__ Wk, const void* __restrict__ Wv,
    const void* __restrict__ Wo, unsigned short* __restrict__ out,
    float* __restrict__ tab)
{
    const int bid = blockIdx.x;
    const int tid = threadIdx.x;

    if (bid >= 4096) {                        // RoPE table: 256 blocks
        const int idx = (bid - 4096) * 256 + tid;   // 0..65535
        const int s = idx >> 5;
        const int f = idx & 31;
        const float invf = __expf((float)f * -0.2878231366f);
        const float ang = (float)s * invf;
        float sn, cs;
        __sincosf(ang, &sn, &cs);
        ((float2*)tab)[idx] = make_float2(cs, sn);
        return;
    }

    const void* src;
    size_t off;
    unsigned short* dst;
    if (bid < 2048) {                         // X: 4M elems, 2048 elems/block
        src = X;
        off = (size_t)bid * 2048;
        dst = out + off;
    } else {                                  // W: 1M elems each, 512 blocks
        const int w  = (bid - 2048) >> 9;
        const size_t lo = (size_t)((bid - 2048) & 511) * 2048;
        src = (w == 0) ? Wq : (w == 1) ? Wk : (w == 2) ? Wv : Wo;
        off = lo;
        dst = out + PER + (size_t)w * (DD * DD) + lo;
    }
    const bool bf = sniff_bf(src);
    const size_t i = off + (size_t)tid * 8;
    if (bf) {
        *(uint4*)(dst + tid * 8) = *(const uint4*)((const unsigned short*)src + i);
    } else {
        float f[8];
        ld4<false>(src, i, f);
        ld4<false>(src, i + 4, f + 4);
        uint4 u;
        u.x = pack2(f[0], f[1]); u.y = pack2(f[2], f[3]);
        u.z = pack2(f[4], f[5]); u.w = pack2(f[6], f[7]);
        *(uint4*)(dst + tid * 8) = u;
    }
}

// ---------------------------------------------------------------------------
// Kernel 1: QKV projection as ONE flat GEMM, M=4096 x N=3072 (Q|K|V), K=1024.
// NEW this round:
//  - BK=32 double-buffered LDS staging (32 KiB total, keeps 3 blocks/CU):
//    tile t+1's global_load_lds issued before computing tile t, ONE barrier
//    per K-step (was 2 + full serial drain).
//  - RoPE epilogue reads the precomputed cos/sin table (TAB=true) instead of
//    64 __sincosf per lane.
// Swizzle for 64B rows: source chunk ^= (row>>1)&3; read chunk qd^((ln>>1)&3).
// ---------------------------------------------------------------------------
template<bool BF, bool TAB>
__device__ __forceinline__ void qkv_body128(
    const void* __restrict__ X,
    const void* __restrict__ Wq, const void* __restrict__ Wk, const void* __restrict__ Wv,
    const int* __restrict__ pos, const float* __restrict__ tab,
    __hip_bfloat16* __restrict__ Qb, __hip_bfloat16* __restrict__ Kb,
    __hip_bfloat16* __restrict__ Vb,
    unsigned short* Sh)                       // 16384 shorts = 32 KiB
{
    const int tid  = threadIdx.x;
    const int lane = tid & 63;
    const int wv   = tid >> 6;
    const int wr   = wv >> 1;
    const int wc   = wv & 1;
    const int ln   = lane & 15;
    const int qd   = lane >> 4;
    const int srow = lane >> 2;               // staging: row within 16-row group
    const int sc4  = lane & 3;                // staging: dest chunk (16B units)

    const int m0  = blockIdx.x * 128;
    const int n0g = blockIdx.y * 128;         // 0..3071
    const int z   = n0g >> 10;                // 0=Q 1=K 2=V
    const int nw  = n0g & (DD - 1);           // col within weight
    const void* W = (z == 0) ? Wq : (z == 1) ? Wk : Wv;

    unsigned short* A0 = Sh;                  // [128][32] each
    unsigned short* A1 = Sh + 4096;
    unsigned short* B0 = Sh + 8192;
    unsigned short* B1 = Sh + 12288;

    auto stage = [&](int k0, unsigned short* Ad, unsigned short* Bd) {
#pragma unroll
        for (int g = 0; g < 2; ++g) {
            const int base = (wv * 2 + g) * 16;
            const int row  = base + srow;
            const int sc   = sc4 ^ ((row >> 1) & 3);   // pre-swizzled source
            const size_t ga = (size_t)(m0 + row) * DD + k0 + sc * 8;
            if (BF) gld16((const unsigned short*)X + ga, Ad + (size_t)base * 32);
            else    *(uint4*)(Ad + (size_t)row * 32 + sc4 * 8) = ld8bf<false>(X, ga);
            const size_t gb = (size_t)(nw + row) * DD + k0 + sc * 8;
            if (BF) gld16((const unsigned short*)W + gb, Bd + (size_t)base * 32);
            else    *(uint4*)(Bd + (size_t)row * 32 + sc4 * 8) = ld8bf<false>(W, gb);
        }
    };

    v4f acc[4][4];
#pragma unroll
    for (int i = 0; i < 4; ++i)
#pragma unroll
        for (int j = 0; j < 4; ++j) acc[i][j] = (v4f){0.f, 0.f, 0.f, 0.f};

    unsigned short *Ac = A0, *An = A1, *Bc = B0, *Bn = B1;
    stage(0, Ac, Bc);
    __syncthreads();

    const int rsw = (ln >> 1) & 3;            // read-side swizzle component

    for (int t = 0; t < 32; ++t) {
        if (t + 1 < 32) stage((t + 1) * 32, An, Bn);

        v8bf a[4], b[4];
#pragma unroll
        for (int mt = 0; mt < 4; ++mt)
            a[mt] = *(const v8bf*)&Ac[(size_t)(wr * 64 + mt * 16 + ln) * 32 +
                                      ((qd ^ rsw)) * 8];
#pragma unroll
        for (int nt = 0; nt < 4; ++nt)
            b[nt] = *(const v8bf*)&Bc[(size_t)(wc * 64 + nt * 16 + ln) * 32 +
                                      ((qd ^ rsw)) * 8];
#pragma unroll
        for (int mt = 0; mt < 4; ++mt)
#pragma unroll
            for (int nt = 0; nt < 4; ++nt)
                acc[mt][nt] = __builtin_amdgcn_mfma_f32_16x16x32_bf16(
                    a[mt], b[nt], acc[mt][nt], 0, 0, 0);

        __syncthreads();   // drains prefetch into An/Bn; frees Ac/Bc
        unsigned short* tp;
        tp = Ac; Ac = An; An = tp;
        tp = Bc; Bc = Bn; Bn = tp;
    }

    const int bb = m0 >> 11;                  // batch (tile never straddles)
    if (z < 2) {
        // ---- Q / K epilogue: RoPE + scattered (B,H,S,DK) store ----
        __hip_bfloat16* Out = z ? Kb : Qb;
        const int head = (nw >> 6) + wc;      // wave's 64 cols = one head
        float invf[4];
        if (!TAB) {
#pragma unroll
            for (int nt = 0; nt < 4; ++nt) {
                const int dk = nt * 16 + ln;
                invf[nt] = __expf((float)(dk >> 1) * -0.2878231366f);
            }
        }
#pragma unroll
        for (int mt = 0; mt < 4; ++mt) {
#pragma unroll
            for (int r = 0; r < 4; ++r) {
                const int m = m0 + wr * 64 + mt * 16 + qd * 4 + r;
                const int s = m & (SS - 1);
                const int pi = pos[m];
                const float p = (float)pi;
                const float2* trow = TAB ? ((const float2*)tab) + (size_t)pi * 32
                                         : nullptr;
#pragma unroll
                for (int nt = 0; nt < 4; ++nt) {
                    const int dk = nt * 16 + ln;
                    const float val = acc[mt][nt][r];
                    float sn, cs;
                    if (TAB) {
                        const float2 t2 = trow[nt * 8 + (ln >> 1)];
                        cs = t2.x; sn = t2.y;
                    } else {
                        const float ang = p * invf[nt];
                        __sincosf(ang, &sn, &cs);
                    }
                    const float prt = __shfl_xor(val, 1);
                    float res = ((dk & 1) == 0) ? (val * cs - prt * sn)
                                                : (prt * sn + val * cs);
                    if (z == 0) res *= 0.125f;   // fold 1/sqrt(dk) into Q
                    Out[((size_t)(bb * HH + head) * SS + s) * DKK + dk] =
                        __float2bfloat16(res);
                }
            }
        }
    } else {
        // ---- V epilogue: per-head transpose via LDS, coalesced (B,H,DK,S) ----
        const int s0 = m0 & (SS - 1);
#pragma unroll
        for (int h2 = 0; h2 < 2; ++h2) {
            __syncthreads();
            if (wc == h2) {
#pragma unroll
                for (int nt = 0; nt < 4; ++nt)
#pragma unroll
                    for (int mt = 0; mt < 4; ++mt)
#pragma unroll
                        for (int r = 0; r < 4; ++r)
                            Sh[(size_t)(nt * 16 + ln) * 136 +
                               wr * 64 + mt * 16 + qd * 4 + r] =
                                f2bfu(acc[mt][nt][r]);
            }
            __syncthreads();
            const int head = (nw >> 6) + h2;
            const int row  = tid >> 2;                 // dk 0..63
            const int c    = (tid & 3) * 32;
            unsigned short* dst = (unsigned short*)Vb +
                ((size_t)(bb * HH + head) * DKK + row) * SS + s0 + c;
            const unsigned short* Ts = Sh + (size_t)row * 136 + c;
#pragma unroll
            for (int j = 0; j < 4; ++j)
                *(uint4*)(dst + j * 8) = *(const uint4*)(Ts + j * 8);
        }
    }
}

__global__ __launch_bounds__(256) void qkv_gemm(
    const void* __restrict__ X,
    const void* __restrict__ Wq, const void* __restrict__ Wk, const void* __restrict__ Wv,
    const int* __restrict__ pos,
    __hip_bfloat16* __restrict__ Qb, __hip_bfloat16* __restrict__ Kb,
    __hip_bfloat16* __restrict__ Vb)
{
    __shared__ unsigned short Sh[16384];
    if (sniff_bf(X)) qkv_body128<true,  false>(X, Wq, Wk, Wv, pos, nullptr, Qb, Kb, Vb, Sh);
    else             qkv_body128<false, false>(X, Wq, Wk, Wv, pos, nullptr, Qb, Kb, Vb, Sh);
}

__global__ __launch_bounds__(256) void qkv_gemm_pc(
    const unsigned short* __restrict__ Xb,
    const unsigned short* __restrict__ Wqb, const unsigned short* __restrict__ Wkb,
    const unsigned short* __restrict__ Wvb,
    const int* __restrict__ pos, const float* __restrict__ tab,
    __hip_bfloat16* __restrict__ Qb, __hip_bfloat16* __restrict__ Kb,
    __hip_bfloat16* __restrict__ Vb)
{
    __shared__ unsigned short Sh[16384];
    qkv_body128<true, true>(Xb, Wqb, Wkb, Wvb, pos, tab, Qb, Kb, Vb, Sh);
}

// ---------------------------------------------------------------------------
// Kernel 2: causal flash attention (unchanged from round 2: dbuf K/V
// prefetch, swapped QK^T, setprio, olay output layout).
// ---------------------------------------------------------------------------
__global__ __launch_bounds__(256) void attn_kernel(
    const __hip_bfloat16* __restrict__ Qb,
    const __hip_bfloat16* __restrict__ Kb,
    const __hip_bfloat16* __restrict__ Vtb,
    unsigned short* __restrict__ Ob, int olay)
{
    __shared__ unsigned short Ks[2][64 * 64];
    __shared__ unsigned short Vs[2][64 * 64];
    __shared__ unsigned short Ps[4][16 * 72];

    const int tid  = threadIdx.x;
    const int bh   = blockIdx.x & 31;
    const int qt   = 31 - (blockIdx.x >> 5);   // heavy tiles first
    const int q0   = qt * 64;
    const int lane = tid & 63;
    const int wv   = tid >> 6;
    const int ln   = lane & 15;
    const int qd   = lane >> 4;
    const int r8   = lane >> 3;
    const int pc   = lane & 7;
    const int lchunk = pc ^ r8;

    const unsigned short* Qu = (const unsigned short*)Qb + (size_t)bh * SS * DKK;
    const unsigned short* Ku = (const unsigned short*)Kb + (size_t)bh * SS * DKK;
    const unsigned short* Vu = (const unsigned short*)Vtb + (size_t)bh * DKK * SS;

    const int qrow = q0 + wv * 16 + ln;
    const v8bf qf0 = *(const v8bf*)(Qu + (size_t)qrow * DKK + qd * 8);
    const v8bf qf1 = *(const v8bf*)(Qu + (size_t)qrow * DKK + 32 + qd * 8);

    auto stage = [&](int t, int b) {
        const int k0 = t * 64;
#pragma unroll
        for (int g = 0; g < 2; ++g) {
            const int row  = wv * 16 + g * 8 + r8;
            const int base = wv * 16 + g * 8;
            gld16(Ku + (size_t)(k0 + row) * DKK + lchunk * 8,
                  Ks[b] + (size_t)base * 64);
            gld16(Vu + (size_t)row * SS + k0 + lchunk * 8,
                  Vs[b] + (size_t)base * 64);
        }
    };

    v4f oacc[4];
#pragma unroll
    for (int n = 0; n < 4; ++n) oacc[n] = (v4f){0.f, 0.f, 0.f, 0.f};
    float lsum = 0.f;

    const int ntiles = qt + 1;
    const int qi = q0 + wv * 16 + ln;          // this lane's query row

    stage(0, 0);
    __syncthreads();

    for (int t = 0; t < ntiles; ++t) {
        const int cur = t & 1;
        if (t + 1 < ntiles) stage(t + 1, cur ^ 1);

        const unsigned short* Kc = Ks[cur];
        const unsigned short* Vc = Vs[cur];

        // ---- QK^T, SWAPPED operands: col=query(ln), row=key(qd*4+r) ----
        v4f s[4];
        __builtin_amdgcn_s_setprio(1);
#pragma unroll
        for (int g = 0; g < 4; ++g) {
            s[g] = (v4f){0.f, 0.f, 0.f, 0.f};
            const int krow = g * 16 + ln;
            const v8bf kf0 = *(const v8bf*)&Kc[(size_t)krow * 64 + ((qd ^ (ln & 7))) * 8];
            const v8bf kf1 = *(const v8bf*)&Kc[(size_t)krow * 64 + (((4 + qd) ^ (ln & 7))) * 8];
            s[g] = __builtin_amdgcn_mfma_f32_16x16x32_bf16(kf0, qf0, s[g], 0, 0, 0);
            s[g] = __builtin_amdgcn_mfma_f32_16x16x32_bf16(kf1, qf1, s[g], 0, 0, 0);
        }
        __builtin_amdgcn_s_setprio(0);

        // ---- softmax (static max): mask only on the diagonal tile ----
        const int k0 = t * 64;
        if (t == qt) {
#pragma unroll
            for (int g = 0; g < 4; ++g)
#pragma unroll
                for (int r = 0; r < 4; ++r) {
                    const int key = k0 + g * 16 + qd * 4 + r;
                    const float sv = (key <= qi) ? s[g][r] : -1e30f;
                    const float p = __expf(sv - 20.f);
                    s[g][r] = p;
                    lsum += p;
                }
        } else {
#pragma unroll
            for (int g = 0; g < 4; ++g)
#pragma unroll
                for (int r = 0; r < 4; ++r) {
                    const float p = __expf(s[g][r] - 20.f);
                    s[g][r] = p;
                    lsum += p;
                }
        }

        // ---- P -> LDS: 4 contiguous bf16 per (g) -> one b64 write ----
        unsigned short* Pw = Ps[wv];
#pragma unroll
        for (int g = 0; g < 4; ++g) {
            uint2 w;
            w.x = pack2(s[g][0], s[g][1]);
            w.y = pack2(s[g][2], s[g][3]);
            *(uint2*)&Pw[(size_t)ln * 72 + g * 16 + qd * 4] = w;
        }

        const v8bf pf0 = *(const v8bf*)&Pw[(size_t)ln * 72 + qd * 8];
        const v8bf pf1 = *(const v8bf*)&Pw[(size_t)ln * 72 + 32 + qd * 8];
        __builtin_amdgcn_s_setprio(1);
#pragma unroll
        for (int n = 0; n < 4; ++n) {
            const int vrow = n * 16 + ln;
            const v8bf vf0 = *(const v8bf*)&Vc[(size_t)vrow * 64 + ((qd ^ (ln & 7))) * 8];
            const v8bf vf1 = *(const v8bf*)&Vc[(size_t)vrow * 64 + (((4 + qd) ^ (ln & 7))) * 8];
            oacc[n] = __builtin_amdgcn_mfma_f32_16x16x32_bf16(pf0, vf0, oacc[n], 0, 0, 0);
            oacc[n] = __builtin_amdgcn_mfma_f32_16x16x32_bf16(pf1, vf1, oacc[n], 0, 0, 0);
        }
        __builtin_amdgcn_s_setprio(0);

        __syncthreads();   // drains next tile's prefetch; frees cur for t+2
    }

    // denom: lane holds partial sum for query ln; reduce across qd groups
    lsum += __shfl_xor(lsum, 16);
    lsum += __shfl_xor(lsum, 32);

#pragma unroll
    for (int r = 0; r < 4; ++r) {
        const float inv = 1.f / __shfl(lsum, qd * 4 + r);
        const int row = q0 + wv * 16 + qd * 4 + r;
        unsigned short* op;
        if (olay) {
            op = Ob + ((size_t)((bh >> 4) * SS + row)) * DD + (bh & 15) * DKK;
        } else {
            op = Ob + ((size_t)bh * SS + row) * DKK;
        }
#pragma unroll
        for (int n = 0; n < 4; ++n)
            op[n * 16 + ln] = f2bfu(oacc[n][r] * inv);
    }
}

// ---------------------------------------------------------------------------
// Kernel 3: output projection (unchanged from round 2: double-buffered LDS,
// ACONT contiguous A-read in Tier A).
// ---------------------------------------------------------------------------
template<bool BFB, bool BFO, bool ACONT>
__device__ __forceinline__ void out_body128(
    const __hip_bfloat16* __restrict__ Ab, const void* __restrict__ Wo,
    void* __restrict__ Cb, float* __restrict__ Cf, int raw,
    unsigned short* Sh)                        // 4 x 8192 shorts = 64 KiB
{
    const int tid  = threadIdx.x;
    const int lane = tid & 63;
    const int wv   = tid >> 6;
    const int wr   = wv >> 1;
    const int wc   = wv & 1;
    const int ln   = lane & 15;
    const int qd   = lane >> 4;
    const int r8   = lane >> 3;
    const int pc   = lane & 7;
    const int lchunk = pc ^ r8;

    const int m0 = blockIdx.x * 128, n0 = blockIdx.y * 128;
    const unsigned short* Au = (const unsigned short*)Ab;

    unsigned short* Abuf[2] = { Sh,               Sh + 2 * 8192 };
    unsigned short* Bbuf[2] = { Sh + 8192,        Sh + 3 * 8192 };

    auto stage = [&](int k0, unsigned short* Ad, unsigned short* Bd) {
#pragma unroll
        for (int g = 0; g < 4; ++g) {
            const int base = (wv * 4 + g) * 8;
            const int row  = base + r8;
            const int m = m0 + row;
            size_t ga;
            if (ACONT) ga = (size_t)m * DD + k0 + lchunk * 8;
            else       ga = ((size_t)((m >> 11) * HH + (k0 >> 6)) * SS + (m & (SS - 1))) * DKK
                            + lchunk * 8;
            gld16(Au + ga, Ad + (size_t)base * 64);
            const size_t gb = (size_t)(n0 + row) * DD + k0 + lchunk * 8;
            if (BFB) gld16((const unsigned short*)Wo + gb, Bd + (size_t)base * 64);
            else     *(uint4*)(Bd + (size_t)row * 64 + pc * 8) = ld8bf<false>(Wo, gb);
        }
    };

    v4f acc[4][4];
#pragma unroll
    for (int i = 0; i < 4; ++i)
#pragma unroll
        for (int j = 0; j < 4; ++j) acc[i][j] = (v4f){0.f, 0.f, 0.f, 0.f};

    stage(0, Abuf[0], Bbuf[0]);
    __syncthreads();

    for (int kk = 0; kk < 16; ++kk) {
        const int cur = kk & 1;
        if (kk + 1 < 16) stage((kk + 1) * 64, Abuf[cur ^ 1], Bbuf[cur ^ 1]);

        const unsigned short* As = Abuf[cur];
        const unsigned short* Bs = Bbuf[cur];
#pragma unroll
        for (int h = 0; h < 2; ++h) {
            v8bf a[4], b[4];
#pragma unroll
            for (int mt = 0; mt < 4; ++mt)
                a[mt] = *(const v8bf*)&As[(size_t)(wr * 64 + mt * 16 + ln) * 64 +
                                          (((h * 4 + qd) ^ (ln & 7))) * 8];
#pragma unroll
            for (int nt = 0; nt < 4; ++nt)
                b[nt] = *(const v8bf*)&Bs[(size_t)(wc * 64 + nt * 16 + ln) * 64 +
                                          (((h * 4 + qd) ^ (ln & 7))) * 8];
#pragma unroll
            for (int mt = 0; mt < 4; ++mt)
#pragma unroll
                for (int nt = 0; nt < 4; ++nt)
                    acc[mt][nt] = __builtin_amdgcn_mfma_f32_16x16x32_bf16(
                        a[mt], b[nt], acc[mt][nt], 0, 0, 0);
        }
        __syncthreads();   // drains prefetch; frees cur buffer
    }

#pragma unroll
    for (int mt = 0; mt < 4; ++mt) {
#pragma unroll
        for (int r = 0; r < 4; ++r) {
            const int m = m0 + wr * 64 + mt * 16 + qd * 4 + r;
#pragma unroll
            for (int nt = 0; nt < 4; ++nt) {
                const int e = n0 + wc * 64 + nt * 16 + ln;
                const size_t idx = (size_t)m * DD + e;
                const float v = acc[mt][nt][r];
                if (raw) Cf[idx] = v;
                else     st1<BFO>(Cb, idx, v);
            }
        }
    }
}

__global__ __launch_bounds__(256) void out_gemm(
    const __hip_bfloat16* __restrict__ Ab, const void* __restrict__ Wo,
    void* __restrict__ Cb, float* __restrict__ Cf, int raw,
    const void* __restrict__ xs)
{
    __shared__ unsigned short Sh[4 * 8192];
    if (sniff_bf(xs)) out_body128<true,  true,  false>(Ab, Wo, Cb, Cf, raw, Sh);
    else              out_body128<false, false, false>(Ab, Wo, Cb, Cf, raw, Sh);
}

__global__ __launch_bounds__(256) void out_gemm_pc(
    const __hip_bfloat16* __restrict__ Ab, const unsigned short* __restrict__ Wob,
    void* __restrict__ Cb, const void* __restrict__ xs)
{
    __shared__ unsigned short Sh[4 * 8192];
    if (sniff_bf(xs)) out_body128<true, true,  true>(Ab, Wob, Cb, nullptr, 0, Sh);
    else              out_body128<true, false, true>(Ab, Wob, Cb, nullptr, 0, Sh);
}

__global__ __launch_bounds__(256) void copy_cast(
    const float* __restrict__ src, void* __restrict__ dst, const void* __restrict__ xs)
{
    const bool bf = sniff_bf(xs);
    const size_t i = (size_t)blockIdx.x * 256 + threadIdx.x;
    const float v = src[i];
    if (bf) ((__hip_bfloat16*)dst)[i] = __float2bfloat16(v);
    else    ((float*)dst)[i] = v;
}

// ---------------------------------------------------------------------------
extern "C" void kernel_launch(void* const* d_in, const int* in_sizes, int n_in,
                              void* d_out, int out_size, void* d_ws, size_t ws_size,
                              hipStream_t stream) {
    (void)in_sizes; (void)n_in; (void)out_size;

    const void* x   = d_in[0];
    const int*  pos = (const int*)d_in[1];
    const void* Wq  = d_in[2];
    const void* Wk  = d_in[3];
    const void* Wv  = d_in[4];
    const void* Wo  = d_in[5];

    char* ws = (char*)d_ws;
    const size_t bpb   = PER * 2;                        // 8 MB per activation buffer
    const size_t castb = (PER + 4 * (size_t)DD * DD) * 2; // 16 MB bf16 casts
    const size_t tabb  = (size_t)SS * 32 * 2 * sizeof(float); // 512 KB RoPE table
    const size_t need_full = 3 * bpb + castb + tabb + 64;

    if (ws_size >= need_full) {
        // ---- Tier A: precast to bf16 + RoPE table; O reuses the dead Xb
        //      region in (B,S,D) layout so out_gemm streams its A operand ----
        __hip_bfloat16* Qb = (__hip_bfloat16*)ws;
        __hip_bfloat16* Kb = Qb + PER;
        __hip_bfloat16* Vb = Kb + PER;                  // V TRANSPOSED (B,H,DK,S)
        unsigned short* cast = (unsigned short*)(ws + 3 * bpb);
        unsigned short* Xb  = cast;                     // dead after qkv
        unsigned short* Wqb = cast + PER;
        unsigned short* Wkb = Wqb + (size_t)DD * DD;
        unsigned short* Wvb = Wkb + (size_t)DD * DD;
        unsigned short* Wob = Wvb + (size_t)DD * DD;
        float* tab = (float*)(cast + PER + 4 * (size_t)DD * DD);
        unsigned short* Obuf = Xb;                      // O in (B,S,D)

        precast<<<dim3(4352), 256, 0, stream>>>(x, Wq, Wk, Wv, Wo, cast, tab);

        dim3 g1(MM / 128, (3 * DD) / 128);              // 32 x 24
        qkv_gemm_pc<<<g1, 256, 0, stream>>>(Xb, Wqb, Wkb, Wvb, pos, tab, Qb, Kb, Vb);

        dim3 g2(32 * 32);
        attn_kernel<<<g2, 256, 0, stream>>>(Qb, Kb, Vb, Obuf, 1);

        dim3 g3(MM / 128, DD / 128);                    // 32 x 8
        out_gemm_pc<<<g3, 256, 0, stream>>>((const __hip_bfloat16*)Obuf, Wob, d_out, x);
    } else if (ws_size >= 3 * bpb + 64) {
        // ---- Tier B: no precast room; dual-dtype GEMMs, O in-place (legacy) ----
        __hip_bfloat16* Qb = (__hip_bfloat16*)ws;
        __hip_bfloat16* Kb = Qb + PER;
        __hip_bfloat16* Vb = Kb + PER;

        dim3 g1(MM / 128, (3 * DD) / 128);
        qkv_gemm<<<g1, 256, 0, stream>>>(x, Wq, Wk, Wv, pos, Qb, Kb, Vb);

        dim3 g2(32 * 32);
        attn_kernel<<<g2, 256, 0, stream>>>(Qb, Kb, Vb, (unsigned short*)Qb, 0);

        dim3 g3(MM / 128, DD / 128);
        out_gemm<<<g3, 256, 0, stream>>>(Qb, Wo, d_out, nullptr, 0, x);
    } else {
        // ---- Tier C: minimal workspace, Q lives in d_out ----
        __hip_bfloat16* Qb = (__hip_bfloat16*)d_out;
        __hip_bfloat16* Kb = (__hip_bfloat16*)ws;
        __hip_bfloat16* Vb = Kb + PER;
        float* Cf = (float*)ws;

        dim3 g1(MM / 128, (3 * DD) / 128);
        qkv_gemm<<<g1, 256, 0, stream>>>(x, Wq, Wk, Wv, pos, Qb, Kb, Vb);

        dim3 g2(32 * 32);
        attn_kernel<<<g2, 256, 0, stream>>>(Qb, Kb, Vb, (unsigned short*)Qb, 0);

        dim3 g3(MM / 128, DD / 128);
        out_gemm<<<g3, 256, 0, stream>>>(Qb, Wo, nullptr, Cf, 1, x);

        copy_cast<<<PER / 256, 256, 0, stream>>>(Cf, d_out, x);
    }
}

// Round 4
// 163.461 us; speedup vs baseline: 1.1186x; 1.1186x over previous
//
#include <hip/hip_runtime.h>
#include <hip/hip_bf16.h>

#define BB 2
#define SS 2048
#define DD 1024
#define HH 16
#define DKK 64
#define MM (BB * SS)                 // 4096
#define PER ((size_t)MM * DD)        // 4194304 elements per activation buffer

typedef __bf16 v8bf __attribute__((ext_vector_type(8)));
typedef float  v4f  __attribute__((ext_vector_type(4)));

// ---------- helpers ----------
__device__ __forceinline__ float bf2f(unsigned int u16) {
    union { unsigned int i; float f; } x;
    x.i = u16 << 16;
    return x.f;
}
__device__ __forceinline__ unsigned int pack2(float a, float b) {
    union { __hip_bfloat16 h; unsigned short u; } x, y;
    x.h = __float2bfloat16(a); y.h = __float2bfloat16(b);
    return (unsigned int)x.u | ((unsigned int)y.u << 16);
}
__device__ __forceinline__ unsigned short f2bfu(float v) {
    union { __hip_bfloat16 h; unsigned short u; } x;
    x.h = __float2bfloat16(v);
    return x.u;
}
template<bool BF>
__device__ __forceinline__ void ld4(const void* p, size_t i, float* f) {
    if (BF) {
        const uint2 u = *(const uint2*)((const unsigned short*)p + i);
        f[0] = bf2f(u.x & 0xffffu); f[1] = bf2f(u.x >> 16);
        f[2] = bf2f(u.y & 0xffffu); f[3] = bf2f(u.y >> 16);
    } else {
        const float4 v = *(const float4*)((const float*)p + i);
        f[0] = v.x; f[1] = v.y; f[2] = v.z; f[3] = v.w;
    }
}
template<bool BF>
__device__ __forceinline__ void st1(void* p, size_t i, float v) {
    if (BF) ((__hip_bfloat16*)p)[i] = __float2bfloat16(v);
    else    ((float*)p)[i] = v;
}
template<bool BF>
__device__ __forceinline__ uint4 ld8bf(const void* p, size_t i) {
    if (BF) return *(const uint4*)((const unsigned short*)p + i);
    float f[8];
    ld4<false>(p, i, f);
    ld4<false>(p, i + 4, f + 4);
    uint4 u;
    u.x = pack2(f[0], f[1]); u.y = pack2(f[2], f[3]);
    u.z = pack2(f[4], f[5]); u.w = pack2(f[6], f[7]);
    return u;
}

// 16B async global->LDS DMA. LDS dest = wave-uniform base + lane*16.
typedef const __attribute__((address_space(1))) void* gas_p;
typedef __attribute__((address_space(3))) void* las_p;
__device__ __forceinline__ void gld16(const void* g, void* l) {
    __builtin_amdgcn_global_load_lds(
        (gas_p)(unsigned long long)g,
        (las_p)(unsigned int)(unsigned long long)l,
        16, 0, 0);
}

// Inline dtype sniff (ballot over identical 64 words -> uniform decision).
__device__ __forceinline__ bool sniff_bf(const void* x) {
    const unsigned int w = ((const unsigned int*)x)[threadIdx.x & 63];
    const int e = (w >> 7) & 0xFF;
    return __popcll(__ballot(e >= 100 && e <= 140)) >= 32;
}

// ---------------------------------------------------------------------------
// Kernel 0: one-time bf16 precast of X and the four weight matrices, PLUS the
// RoPE cos/sin table (2048 positions x 32 freqs, float2), computed with the
// exact same __expf/__sincosf sequence as the original epilogue.
// ---------------------------------------------------------------------------
__global__ __launch_bounds__(256) void precast(
    const void* __restrict__ X,  const void* __restrict__ Wq,
    const void* __restrict__ Wk, const void* __restrict__ Wv,
    const void* __restrict__ Wo, unsigned short* __restrict__ out,
    float* __restrict__ tab)
{
    const int bid = blockIdx.x;
    const int tid = threadIdx.x;

    if (bid >= 4096) {                        // RoPE table: 256 blocks
        const int idx = (bid - 4096) * 256 + tid;   // 0..65535
        const int s = idx >> 5;
        const int f = idx & 31;
        const float invf = __expf((float)f * -0.2878231366f);
        const float ang = (float)s * invf;
        float sn, cs;
        __sincosf(ang, &sn, &cs);
        ((float2*)tab)[idx] = make_float2(cs, sn);
        return;
    }

    const void* src;
    size_t off;
    unsigned short* dst;
    if (bid < 2048) {                         // X: 4M elems, 2048 elems/block
        src = X;
        off = (size_t)bid * 2048;
        dst = out + off;
    } else {                                  // W: 1M elems each, 512 blocks
        const int w  = (bid - 2048) >> 9;
        const size_t lo = (size_t)((bid - 2048) & 511) * 2048;
        src = (w == 0) ? Wq : (w == 1) ? Wk : (w == 2) ? Wv : Wo;
        off = lo;
        dst = out + PER + (size_t)w * (DD * DD) + lo;
    }
    const bool bf = sniff_bf(src);
    const size_t i = off + (size_t)tid * 8;
    if (bf) {
        *(uint4*)(dst + tid * 8) = *(const uint4*)((const unsigned short*)src + i);
    } else {
        float f[8];
        ld4<false>(src, i, f);
        ld4<false>(src, i + 4, f + 4);
        uint4 u;
        u.x = pack2(f[0], f[1]); u.y = pack2(f[2], f[3]);
        u.z = pack2(f[4], f[5]); u.w = pack2(f[6], f[7]);
        *(uint4*)(dst + tid * 8) = u;
    }
}

// ---------------------------------------------------------------------------
// Kernel 1: QKV projection as ONE flat GEMM, M=4096 x N=3072 (Q|K|V), K=1024.
// Round-2 proven geometry (BK=64, 128x128 tile, 4 waves, lchunk=pc^r8 source
// pre-swizzle, (h*4+qd)^(ln&7) read swizzle) PLUS this round:
//  - T4 counted-vmcnt double-buffer: prefetch next K-tile, s_waitcnt vmcnt(8)
//    (current tile's loads only; prefetch stays IN FLIGHT across the raw
//    s_barrier), 32 MFMA, raw s_barrier. No vmcnt(0) drain in the main loop.
//  - RoPE table epilogue (TAB).
// LDS 64 KiB -> 2 blocks/CU; the pipeline replaces the lost TLP.
// ---------------------------------------------------------------------------
template<bool BF, bool TAB>
__device__ __forceinline__ void qkv_body128(
    const void* __restrict__ X,
    const void* __restrict__ Wq, const void* __restrict__ Wk, const void* __restrict__ Wv,
    const int* __restrict__ pos, const float* __restrict__ tab,
    __hip_bfloat16* __restrict__ Qb, __hip_bfloat16* __restrict__ Kb,
    __hip_bfloat16* __restrict__ Vb,
    unsigned short* Sh)                       // 32768 shorts = 64 KiB
{
    const int tid  = threadIdx.x;
    const int lane = tid & 63;
    const int wv   = tid >> 6;
    const int wr   = wv >> 1;
    const int wc   = wv & 1;
    const int ln   = lane & 15;
    const int qd   = lane >> 4;
    const int r8   = lane >> 3;
    const int pc   = lane & 7;
    const int lchunk = pc ^ r8;

    const int m0  = blockIdx.x * 128;
    const int n0g = blockIdx.y * 128;         // 0..3071
    const int z   = n0g >> 10;                // 0=Q 1=K 2=V
    const int nw  = n0g & (DD - 1);           // col within weight
    const void* W = (z == 0) ? Wq : (z == 1) ? Wk : Wv;

    unsigned short *Ac = Sh,         *An = Sh + 8192;
    unsigned short *Bc = Sh + 16384, *Bn = Sh + 24576;

    auto stage = [&](int k0, unsigned short* Ad, unsigned short* Bd) {
#pragma unroll
        for (int g = 0; g < 4; ++g) {
            const int base = (wv * 4 + g) * 8;        // 8-row group
            const int row  = base + r8;
            const size_t ga = (size_t)(m0 + row) * DD + k0 + lchunk * 8;
            if (BF) gld16((const unsigned short*)X + ga, Ad + (size_t)base * 64);
            else    *(uint4*)(Ad + (size_t)row * 64 + pc * 8) = ld8bf<false>(X, ga);
            const size_t gb = (size_t)(nw + row) * DD + k0 + lchunk * 8;
            if (BF) gld16((const unsigned short*)W + gb, Bd + (size_t)base * 64);
            else    *(uint4*)(Bd + (size_t)row * 64 + pc * 8) = ld8bf<false>(W, gb);
        }
    };

    v4f acc[4][4];
#pragma unroll
    for (int i = 0; i < 4; ++i)
#pragma unroll
        for (int j = 0; j < 4; ++j) acc[i][j] = (v4f){0.f, 0.f, 0.f, 0.f};

    stage(0, Ac, Bc);                          // 8 loads in flight

    for (int t = 0; t < 16; ++t) {
        const bool pf = (t + 1 < 16);
        if (pf) stage((t + 1) * 64, An, Bn);   // +8 -> 16 in flight

        if (BF) {
            // wait ONLY the current tile's 8 loads; keep prefetch in flight
            if (pf) asm volatile("s_waitcnt vmcnt(8)" ::: "memory");
            else    asm volatile("s_waitcnt vmcnt(0)" ::: "memory");
            __builtin_amdgcn_s_barrier();
            asm volatile("" ::: "memory");
        } else {
            __syncthreads();                   // fallback tier: full drain
        }

        __builtin_amdgcn_s_setprio(1);
#pragma unroll
        for (int h = 0; h < 2; ++h) {
            v8bf a[4], b[4];
#pragma unroll
            for (int mt = 0; mt < 4; ++mt)
                a[mt] = *(const v8bf*)&Ac[(size_t)(wr * 64 + mt * 16 + ln) * 64 +
                                          (((h * 4 + qd) ^ (ln & 7))) * 8];
#pragma unroll
            for (int nt = 0; nt < 4; ++nt)
                b[nt] = *(const v8bf*)&Bc[(size_t)(wc * 64 + nt * 16 + ln) * 64 +
                                          (((h * 4 + qd) ^ (ln & 7))) * 8];
#pragma unroll
            for (int mt = 0; mt < 4; ++mt)
#pragma unroll
                for (int nt = 0; nt < 4; ++nt)
                    acc[mt][nt] = __builtin_amdgcn_mfma_f32_16x16x32_bf16(
                        a[mt], b[nt], acc[mt][nt], 0, 0, 0);
        }
        __builtin_amdgcn_s_setprio(0);

        if (BF) {
            asm volatile("" ::: "memory");
            __builtin_amdgcn_s_barrier();      // reads done before overwrite
        } else {
            __syncthreads();
        }

        unsigned short* tp;
        tp = Ac; Ac = An; An = tp;
        tp = Bc; Bc = Bn; Bn = tp;
    }

    const int bb = m0 >> 11;                  // batch (tile never straddles)
    if (z < 2) {
        // ---- Q / K epilogue: RoPE (table) + scattered (B,H,S,DK) store ----
        __hip_bfloat16* Out = z ? Kb : Qb;
        const int head = (nw >> 6) + wc;      // wave's 64 cols = one head
        float invf[4];
        if (!TAB) {
#pragma unroll
            for (int nt = 0; nt < 4; ++nt) {
                const int dk = nt * 16 + ln;
                invf[nt] = __expf((float)(dk >> 1) * -0.2878231366f);
            }
        }
#pragma unroll
        for (int mt = 0; mt < 4; ++mt) {
#pragma unroll
            for (int r = 0; r < 4; ++r) {
                const int m = m0 + wr * 64 + mt * 16 + qd * 4 + r;
                const int s = m & (SS - 1);
                const int pi = pos[m];
                const float p = (float)pi;
                const float2* trow = TAB ? ((const float2*)tab) + (size_t)pi * 32
                                         : nullptr;
#pragma unroll
                for (int nt = 0; nt < 4; ++nt) {
                    const int dk = nt * 16 + ln;
                    const float val = acc[mt][nt][r];
                    float sn, cs;
                    if (TAB) {
                        const float2 t2 = trow[nt * 8 + (ln >> 1)];
                        cs = t2.x; sn = t2.y;
                    } else {
                        const float ang = p * invf[nt];
                        __sincosf(ang, &sn, &cs);
                    }
                    const float prt = __shfl_xor(val, 1);
                    float res = ((dk & 1) == 0) ? (val * cs - prt * sn)
                                                : (prt * sn + val * cs);
                    if (z == 0) res *= 0.125f;   // fold 1/sqrt(dk) into Q
                    Out[((size_t)(bb * HH + head) * SS + s) * DKK + dk] =
                        __float2bfloat16(res);
                }
            }
        }
    } else {
        // ---- V epilogue: per-head transpose via LDS, coalesced (B,H,DK,S) ----
        const int s0 = m0 & (SS - 1);
#pragma unroll
        for (int h2 = 0; h2 < 2; ++h2) {
            __syncthreads();
            if (wc == h2) {
#pragma unroll
                for (int nt = 0; nt < 4; ++nt)
#pragma unroll
                    for (int mt = 0; mt < 4; ++mt)
#pragma unroll
                        for (int r = 0; r < 4; ++r)
                            Sh[(size_t)(nt * 16 + ln) * 136 +
                               wr * 64 + mt * 16 + qd * 4 + r] =
                                f2bfu(acc[mt][nt][r]);
            }
            __syncthreads();
            const int head = (nw >> 6) + h2;
            const int row  = tid >> 2;                 // dk 0..63
            const int c    = (tid & 3) * 32;
            unsigned short* dst = (unsigned short*)Vb +
                ((size_t)(bb * HH + head) * DKK + row) * SS + s0 + c;
            const unsigned short* Ts = Sh + (size_t)row * 136 + c;
#pragma unroll
            for (int j = 0; j < 4; ++j)
                *(uint4*)(dst + j * 8) = *(const uint4*)(Ts + j * 8);
        }
    }
}

__global__ __launch_bounds__(256) void qkv_gemm(
    const void* __restrict__ X,
    const void* __restrict__ Wq, const void* __restrict__ Wk, const void* __restrict__ Wv,
    const int* __restrict__ pos,
    __hip_bfloat16* __restrict__ Qb, __hip_bfloat16* __restrict__ Kb,
    __hip_bfloat16* __restrict__ Vb)
{
    __shared__ unsigned short Sh[32768];
    if (sniff_bf(X)) qkv_body128<true,  false>(X, Wq, Wk, Wv, pos, nullptr, Qb, Kb, Vb, Sh);
    else             qkv_body128<false, false>(X, Wq, Wk, Wv, pos, nullptr, Qb, Kb, Vb, Sh);
}

__global__ __launch_bounds__(256) void qkv_gemm_pc(
    const unsigned short* __restrict__ Xb,
    const unsigned short* __restrict__ Wqb, const unsigned short* __restrict__ Wkb,
    const unsigned short* __restrict__ Wvb,
    const int* __restrict__ pos, const float* __restrict__ tab,
    __hip_bfloat16* __restrict__ Qb, __hip_bfloat16* __restrict__ Kb,
    __hip_bfloat16* __restrict__ Vb)
{
    __shared__ unsigned short Sh[32768];
    qkv_body128<true, true>(Xb, Wqb, Wkb, Wvb, pos, tab, Qb, Kb, Vb, Sh);
}

// ---------------------------------------------------------------------------
// Kernel 2: causal flash attention (unchanged from round 2: dbuf K/V
// prefetch, swapped QK^T, setprio, olay output layout).
// ---------------------------------------------------------------------------
__global__ __launch_bounds__(256) void attn_kernel(
    const __hip_bfloat16* __restrict__ Qb,
    const __hip_bfloat16* __restrict__ Kb,
    const __hip_bfloat16* __restrict__ Vtb,
    unsigned short* __restrict__ Ob, int olay)
{
    __shared__ unsigned short Ks[2][64 * 64];
    __shared__ unsigned short Vs[2][64 * 64];
    __shared__ unsigned short Ps[4][16 * 72];

    const int tid  = threadIdx.x;
    const int bh   = blockIdx.x & 31;
    const int qt   = 31 - (blockIdx.x >> 5);   // heavy tiles first
    const int q0   = qt * 64;
    const int lane = tid & 63;
    const int wv   = tid >> 6;
    const int ln   = lane & 15;
    const int qd   = lane >> 4;
    const int r8   = lane >> 3;
    const int pc   = lane & 7;
    const int lchunk = pc ^ r8;

    const unsigned short* Qu = (const unsigned short*)Qb + (size_t)bh * SS * DKK;
    const unsigned short* Ku = (const unsigned short*)Kb + (size_t)bh * SS * DKK;
    const unsigned short* Vu = (const unsigned short*)Vtb + (size_t)bh * DKK * SS;

    const int qrow = q0 + wv * 16 + ln;
    const v8bf qf0 = *(const v8bf*)(Qu + (size_t)qrow * DKK + qd * 8);
    const v8bf qf1 = *(const v8bf*)(Qu + (size_t)qrow * DKK + 32 + qd * 8);

    auto stage = [&](int t, int b) {
        const int k0 = t * 64;
#pragma unroll
        for (int g = 0; g < 2; ++g) {
            const int row  = wv * 16 + g * 8 + r8;
            const int base = wv * 16 + g * 8;
            gld16(Ku + (size_t)(k0 + row) * DKK + lchunk * 8,
                  Ks[b] + (size_t)base * 64);
            gld16(Vu + (size_t)row * SS + k0 + lchunk * 8,
                  Vs[b] + (size_t)base * 64);
        }
    };

    v4f oacc[4];
#pragma unroll
    for (int n = 0; n < 4; ++n) oacc[n] = (v4f){0.f, 0.f, 0.f, 0.f};
    float lsum = 0.f;

    const int ntiles = qt + 1;
    const int qi = q0 + wv * 16 + ln;          // this lane's query row

    stage(0, 0);
    __syncthreads();

    for (int t = 0; t < ntiles; ++t) {
        const int cur = t & 1;
        if (t + 1 < ntiles) stage(t + 1, cur ^ 1);

        const unsigned short* Kc = Ks[cur];
        const unsigned short* Vc = Vs[cur];

        // ---- QK^T, SWAPPED operands: col=query(ln), row=key(qd*4+r) ----
        v4f s[4];
        __builtin_amdgcn_s_setprio(1);
#pragma unroll
        for (int g = 0; g < 4; ++g) {
            s[g] = (v4f){0.f, 0.f, 0.f, 0.f};
            const int krow = g * 16 + ln;
            const v8bf kf0 = *(const v8bf*)&Kc[(size_t)krow * 64 + ((qd ^ (ln & 7))) * 8];
            const v8bf kf1 = *(const v8bf*)&Kc[(size_t)krow * 64 + (((4 + qd) ^ (ln & 7))) * 8];
            s[g] = __builtin_amdgcn_mfma_f32_16x16x32_bf16(kf0, qf0, s[g], 0, 0, 0);
            s[g] = __builtin_amdgcn_mfma_f32_16x16x32_bf16(kf1, qf1, s[g], 0, 0, 0);
        }
        __builtin_amdgcn_s_setprio(0);

        // ---- softmax (static max): mask only on the diagonal tile ----
        const int k0 = t * 64;
        if (t == qt) {
#pragma unroll
            for (int g = 0; g < 4; ++g)
#pragma unroll
                for (int r = 0; r < 4; ++r) {
                    const int key = k0 + g * 16 + qd * 4 + r;
                    const float sv = (key <= qi) ? s[g][r] : -1e30f;
                    const float p = __expf(sv - 20.f);
                    s[g][r] = p;
                    lsum += p;
                }
        } else {
#pragma unroll
            for (int g = 0; g < 4; ++g)
#pragma unroll
                for (int r = 0; r < 4; ++r) {
                    const float p = __expf(s[g][r] - 20.f);
                    s[g][r] = p;
                    lsum += p;
                }
        }

        // ---- P -> LDS: 4 contiguous bf16 per (g) -> one b64 write ----
        unsigned short* Pw = Ps[wv];
#pragma unroll
        for (int g = 0; g < 4; ++g) {
            uint2 w;
            w.x = pack2(s[g][0], s[g][1]);
            w.y = pack2(s[g][2], s[g][3]);
            *(uint2*)&Pw[(size_t)ln * 72 + g * 16 + qd * 4] = w;
        }

        const v8bf pf0 = *(const v8bf*)&Pw[(size_t)ln * 72 + qd * 8];
        const v8bf pf1 = *(const v8bf*)&Pw[(size_t)ln * 72 + 32 + qd * 8];
        __builtin_amdgcn_s_setprio(1);
#pragma unroll
        for (int n = 0; n < 4; ++n) {
            const int vrow = n * 16 + ln;
            const v8bf vf0 = *(const v8bf*)&Vc[(size_t)vrow * 64 + ((qd ^ (ln & 7))) * 8];
            const v8bf vf1 = *(const v8bf*)&Vc[(size_t)vrow * 64 + (((4 + qd) ^ (ln & 7))) * 8];
            oacc[n] = __builtin_amdgcn_mfma_f32_16x16x32_bf16(pf0, vf0, oacc[n], 0, 0, 0);
            oacc[n] = __builtin_amdgcn_mfma_f32_16x16x32_bf16(pf1, vf1, oacc[n], 0, 0, 0);
        }
        __builtin_amdgcn_s_setprio(0);

        __syncthreads();   // drains next tile's prefetch; frees cur for t+2
    }

    // denom: lane holds partial sum for query ln; reduce across qd groups
    lsum += __shfl_xor(lsum, 16);
    lsum += __shfl_xor(lsum, 32);

#pragma unroll
    for (int r = 0; r < 4; ++r) {
        const float inv = 1.f / __shfl(lsum, qd * 4 + r);
        const int row = q0 + wv * 16 + qd * 4 + r;
        unsigned short* op;
        if (olay) {
            op = Ob + ((size_t)((bh >> 4) * SS + row)) * DD + (bh & 15) * DKK;
        } else {
            op = Ob + ((size_t)bh * SS + row) * DKK;
        }
#pragma unroll
        for (int n = 0; n < 4; ++n)
            op[n * 16 + ln] = f2bfu(oacc[n][r] * inv);
    }
}

// ---------------------------------------------------------------------------
// Kernel 3: output projection. Dbuf from round 2, NEW: counted-vmcnt raw
// barriers replace the full-drain __syncthreads (same T4 transform as qkv).
// ---------------------------------------------------------------------------
template<bool BFB, bool BFO, bool ACONT>
__device__ __forceinline__ void out_body128(
    const __hip_bfloat16* __restrict__ Ab, const void* __restrict__ Wo,
    void* __restrict__ Cb, float* __restrict__ Cf, int raw,
    unsigned short* Sh)                        // 4 x 8192 shorts = 64 KiB
{
    const int tid  = threadIdx.x;
    const int lane = tid & 63;
    const int wv   = tid >> 6;
    const int wr   = wv >> 1;
    const int wc   = wv & 1;
    const int ln   = lane & 15;
    const int qd   = lane >> 4;
    const int r8   = lane >> 3;
    const int pc   = lane & 7;
    const int lchunk = pc ^ r8;

    const int m0 = blockIdx.x * 128, n0 = blockIdx.y * 128;
    const unsigned short* Au = (const unsigned short*)Ab;

    unsigned short *Ac = Sh,         *An = Sh + 2 * 8192;
    unsigned short *Bc = Sh + 8192,  *Bn = Sh + 3 * 8192;

    auto stage = [&](int k0, unsigned short* Ad, unsigned short* Bd) {
#pragma unroll
        for (int g = 0; g < 4; ++g) {
            const int base = (wv * 4 + g) * 8;
            const int row  = base + r8;
            const int m = m0 + row;
            size_t ga;
            if (ACONT) ga = (size_t)m * DD + k0 + lchunk * 8;
            else       ga = ((size_t)((m >> 11) * HH + (k0 >> 6)) * SS + (m & (SS - 1))) * DKK
                            + lchunk * 8;
            gld16(Au + ga, Ad + (size_t)base * 64);
            const size_t gb = (size_t)(n0 + row) * DD + k0 + lchunk * 8;
            if (BFB) gld16((const unsigned short*)Wo + gb, Bd + (size_t)base * 64);
            else     *(uint4*)(Bd + (size_t)row * 64 + pc * 8) = ld8bf<false>(Wo, gb);
        }
    };

    v4f acc[4][4];
#pragma unroll
    for (int i = 0; i < 4; ++i)
#pragma unroll
        for (int j = 0; j < 4; ++j) acc[i][j] = (v4f){0.f, 0.f, 0.f, 0.f};

    stage(0, Ac, Bc);

    for (int kk = 0; kk < 16; ++kk) {
        const bool pf = (kk + 1 < 16);
        if (pf) stage((kk + 1) * 64, An, Bn);

        if (BFB) {
            if (pf) asm volatile("s_waitcnt vmcnt(8)" ::: "memory");
            else    asm volatile("s_waitcnt vmcnt(0)" ::: "memory");
            __builtin_amdgcn_s_barrier();
            asm volatile("" ::: "memory");
        } else {
            __syncthreads();
        }

        __builtin_amdgcn_s_setprio(1);
#pragma unroll
        for (int h = 0; h < 2; ++h) {
            v8bf a[4], b[4];
#pragma unroll
            for (int mt = 0; mt < 4; ++mt)
                a[mt] = *(const v8bf*)&Ac[(size_t)(wr * 64 + mt * 16 + ln) * 64 +
                                          (((h * 4 + qd) ^ (ln & 7))) * 8];
#pragma unroll
            for (int nt = 0; nt < 4; ++nt)
                b[nt] = *(const v8bf*)&Bc[(size_t)(wc * 64 + nt * 16 + ln) * 64 +
                                          (((h * 4 + qd) ^ (ln & 7))) * 8];
#pragma unroll
            for (int mt = 0; mt < 4; ++mt)
#pragma unroll
                for (int nt = 0; nt < 4; ++nt)
                    acc[mt][nt] = __builtin_amdgcn_mfma_f32_16x16x32_bf16(
                        a[mt], b[nt], acc[mt][nt], 0, 0, 0);
        }
        __builtin_amdgcn_s_setprio(0);

        if (BFB) {
            asm volatile("" ::: "memory");
            __builtin_amdgcn_s_barrier();
        } else {
            __syncthreads();
        }

        unsigned short* tp;
        tp = Ac; Ac = An; An = tp;
        tp = Bc; Bc = Bn; Bn = tp;
    }

#pragma unroll
    for (int mt = 0; mt < 4; ++mt) {
#pragma unroll
        for (int r = 0; r < 4; ++r) {
            const int m = m0 + wr * 64 + mt * 16 + qd * 4 + r;
#pragma unroll
            for (int nt = 0; nt < 4; ++nt) {
                const int e = n0 + wc * 64 + nt * 16 + ln;
                const size_t idx = (size_t)m * DD + e;
                const float v = acc[mt][nt][r];
                if (raw) Cf[idx] = v;
                else     st1<BFO>(Cb, idx, v);
            }
        }
    }
}

__global__ __launch_bounds__(256) void out_gemm(
    const __hip_bfloat16* __restrict__ Ab, const void* __restrict__ Wo,
    void* __restrict__ Cb, float* __restrict__ Cf, int raw,
    const void* __restrict__ xs)
{
    __shared__ unsigned short Sh[4 * 8192];
    if (sniff_bf(xs)) out_body128<true,  true,  false>(Ab, Wo, Cb, Cf, raw, Sh);
    else              out_body128<false, false, false>(Ab, Wo, Cb, Cf, raw, Sh);
}

__global__ __launch_bounds__(256) void out_gemm_pc(
    const __hip_bfloat16* __restrict__ Ab, const unsigned short* __restrict__ Wob,
    void* __restrict__ Cb, const void* __restrict__ xs)
{
    __shared__ unsigned short Sh[4 * 8192];
    if (sniff_bf(xs)) out_body128<true, true,  true>(Ab, Wob, Cb, nullptr, 0, Sh);
    else              out_body128<true, false, true>(Ab, Wob, Cb, nullptr, 0, Sh);
}

__global__ __launch_bounds__(256) void copy_cast(
    const float* __restrict__ src, void* __restrict__ dst, const void* __restrict__ xs)
{
    const bool bf = sniff_bf(xs);
    const size_t i = (size_t)blockIdx.x * 256 + threadIdx.x;
    const float v = src[i];
    if (bf) ((__hip_bfloat16*)dst)[i] = __float2bfloat16(v);
    else    ((float*)dst)[i] = v;
}

// ---------------------------------------------------------------------------
extern "C" void kernel_launch(void* const* d_in, const int* in_sizes, int n_in,
                              void* d_out, int out_size, void* d_ws, size_t ws_size,
                              hipStream_t stream) {
    (void)in_sizes; (void)n_in; (void)out_size;

    const void* x   = d_in[0];
    const int*  pos = (const int*)d_in[1];
    const void* Wq  = d_in[2];
    const void* Wk  = d_in[3];
    const void* Wv  = d_in[4];
    const void* Wo  = d_in[5];

    char* ws = (char*)d_ws;
    const size_t bpb   = PER * 2;                        // 8 MB per activation buffer
    const size_t castb = (PER + 4 * (size_t)DD * DD) * 2; // 16 MB bf16 casts
    const size_t tabb  = (size_t)SS * 32 * 2 * sizeof(float); // 512 KB RoPE table
    const size_t need_full = 3 * bpb + castb + tabb + 64;

    if (ws_size >= need_full) {
        // ---- Tier A: precast to bf16 + RoPE table; O reuses the dead Xb
        //      region in (B,S,D) layout so out_gemm streams its A operand ----
        __hip_bfloat16* Qb = (__hip_bfloat16*)ws;
        __hip_bfloat16* Kb = Qb + PER;
        __hip_bfloat16* Vb = Kb + PER;                  // V TRANSPOSED (B,H,DK,S)
        unsigned short* cast = (unsigned short*)(ws + 3 * bpb);
        unsigned short* Xb  = cast;                     // dead after qkv
        unsigned short* Wqb = cast + PER;
        unsigned short* Wkb = Wqb + (size_t)DD * DD;
        unsigned short* Wvb = Wkb + (size_t)DD * DD;
        unsigned short* Wob = Wvb + (size_t)DD * DD;
        float* tab = (float*)(cast + PER + 4 * (size_t)DD * DD);
        unsigned short* Obuf = Xb;                      // O in (B,S,D)

        precast<<<dim3(4352), 256, 0, stream>>>(x, Wq, Wk, Wv, Wo, cast, tab);

        dim3 g1(MM / 128, (3 * DD) / 128);              // 32 x 24
        qkv_gemm_pc<<<g1, 256, 0, stream>>>(Xb, Wqb, Wkb, Wvb, pos, tab, Qb, Kb, Vb);

        dim3 g2(32 * 32);
        attn_kernel<<<g2, 256, 0, stream>>>(Qb, Kb, Vb, Obuf, 1);

        dim3 g3(MM / 128, DD / 128);                    // 32 x 8
        out_gemm_pc<<<g3, 256, 0, stream>>>((const __hip_bfloat16*)Obuf, Wob, d_out, x);
    } else if (ws_size >= 3 * bpb + 64) {
        // ---- Tier B: no precast room; dual-dtype GEMMs, O in-place (legacy) ----
        __hip_bfloat16* Qb = (__hip_bfloat16*)ws;
        __hip_bfloat16* Kb = Qb + PER;
        __hip_bfloat16* Vb = Kb + PER;

        dim3 g1(MM / 128, (3 * DD) / 128);
        qkv_gemm<<<g1, 256, 0, stream>>>(x, Wq, Wk, Wv, pos, Qb, Kb, Vb);

        dim3 g2(32 * 32);
        attn_kernel<<<g2, 256, 0, stream>>>(Qb, Kb, Vb, (unsigned short*)Qb, 0);

        dim3 g3(MM / 128, DD / 128);
        out_gemm<<<g3, 256, 0, stream>>>(Qb, Wo, d_out, nullptr, 0, x);
    } else {
        // ---- Tier C: minimal workspace, Q lives in d_out ----
        __hip_bfloat16* Qb = (__hip_bfloat16*)d_out;
        __hip_bfloat16* Kb = (__hip_bfloat16*)ws;
        __hip_bfloat16* Vb = Kb + PER;
        float* Cf = (float*)ws;

        dim3 g1(MM / 128, (3 * DD) / 128);
        qkv_gemm<<<g1, 256, 0, stream>>>(x, Wq, Wk, Wv, pos, Qb, Kb, Vb);

        dim3 g2(32 * 32);
        attn_kernel<<<g2, 256, 0, stream>>>(Qb, Kb, Vb, (unsigned short*)Qb, 0);

        dim3 g3(MM / 128, DD / 128);
        out_gemm<<<g3, 256, 0, stream>>>(Qb, Wo, nullptr, Cf, 1, x);

        copy_cast<<<PER / 256, 256, 0, stream>>>(Cf, d_out, x);
    }
}